// Round 6
// baseline (336.229 us; speedup 1.0000x reference)
//
#include <hip/hip_runtime.h>
#include <float.h>

#define DIM      256
#define KCODES   4096
#define NSEQ     2048
#define IDXOFF   4194304
#define LOSS_OFF 4210688
#define NTILE    64
#define THRESH   1.0e-3f
#define RCAP     1024
#define LOSS_SCALE (0.25f / 4194304.0f)

typedef __attribute__((ext_vector_type(8))) short short8;
typedef __attribute__((ext_vector_type(4))) float f32x4;
typedef __attribute__((ext_vector_type(4))) unsigned short us4;

// f32 -> bf16(hi) + bf16(lo) split, RNE
__device__ __forceinline__ void bsplit(float x, unsigned short& hi, unsigned short& lo) {
  union { float f; unsigned u; } a; a.f = x;
  unsigned r = a.u + 0x7FFFu + ((a.u >> 16) & 1u);
  hi = (unsigned short)(r >> 16);
  union { unsigned u; float f; } h; h.u = ((unsigned)hi) << 16;
  float res = x - h.f;
  union { float f; unsigned u; } b2; b2.f = res;
  unsigned r2 = b2.u + 0x7FFFu + ((b2.u >> 16) & 1u);
  lo = (unsigned short)(r2 >> 16);
}

__device__ __forceinline__ void gload_lds16(const void* g, void* l) {
  __builtin_amdgcn_global_load_lds(
      (const __attribute__((address_space(1))) unsigned*)g,
      (__attribute__((address_space(3))) unsigned*)l, 16, 0, 0);
}

// ---- combined prep: blocks 0..511 permute/split codebook; 512..527 norms ----
// LDS-tile layout (64 KB per 64-code tile ti):
//   byte = ((st*4 + ch)*2 + hl)*1024 + l*16,  l = kg*16 + col
//   holds cb[ti*64 + ch*16 + col][st*32 + kg*8 + j], j=0..7, hl: 0=hi 1=lo
__global__ __launch_bounds__(256) void fsq_prep(const float* __restrict__ cb,
                                                char* __restrict__ cbsplit,
                                                float* __restrict__ cn32,
                                                double* __restrict__ cn64,
                                                int* __restrict__ rcount,
                                                float* __restrict__ out) {
  const int bid = blockIdx.x;
  const int t   = threadIdx.x;
  if (bid < 512) {
    int tid = bid * 256 + t;           // 0..131071
    int ti  = tid >> 11;
    int c   = tid & 2047;              // (st*4+ch)*64 + l
    int st  = c >> 8;
    int ch  = (c >> 6) & 3;
    int l   = c & 63;
    int kg  = l >> 4, col = l & 15;
    int code  = ti * 64 + ch * 16 + col;
    int dbase = st * 32 + kg * 8;
    const float4* p = (const float4*)(cb + (size_t)code * DIM + dbase);
    float4 aa = p[0], bb = p[1];
    float vv[8] = {aa.x, aa.y, aa.z, aa.w, bb.x, bb.y, bb.z, bb.w};
    short8 h8, l8;
#pragma unroll
    for (int j = 0; j < 8; ++j) {
      unsigned short hh, lo2;
      bsplit(vv[j], hh, lo2);
      h8[j] = (short)hh; l8[j] = (short)lo2;
    }
    char* tb = cbsplit + (size_t)ti * 65536 + (c >> 6) * 2048 + l * 16;
    *(short8*)tb = h8;
    *(short8*)(tb + 1024) = l8;
  } else {
    int code = (bid - 512) * 256 + t;
    const float4* c4 = reinterpret_cast<const float4*>(cb + (size_t)code * DIM);
    double s = 0.0;
#pragma unroll 8
    for (int i = 0; i < DIM / 4; ++i) {
      float4 v = c4[i];
      s += (double)v.x * v.x + (double)v.y * v.y + (double)v.z * v.z + (double)v.w * v.w;
    }
    cn32[code] = (float)s;
    cn64[code] = s;
    if (code == 0) { *rcount = 0; out[LOSS_OFF] = 0.0f; }
  }
}

// ---- main: MFMA screen (R=2 rowsets, 4-way code split) + fused output ----
__global__ __launch_bounds__(512, 2) void fsq_score(
    const float* __restrict__ x, const float* __restrict__ cb,
    const char* __restrict__ cbsplit, const float* __restrict__ cn32,
    int* __restrict__ idxws, int* __restrict__ rcount, int* __restrict__ rlist,
    float* __restrict__ out) {
  __shared__ __align__(16) short tiles[2][32768];   // 128 KB dbuf
  __shared__ float m1[8][32], m2[8][32];
  __shared__ int   mi[8][32];
  __shared__ int   sIdx[64];
  __shared__ float wl[8];

  const int t   = threadIdx.x;
  const int wid = t >> 6;
  const int l   = t & 63;
  const int col = l & 15;
  const int kg  = l >> 4;
  const int rg  = wid >> 2;      // 0..1 : 32-row group
  const int ch  = wid & 3;       // 0..3 : 16-code slice of each tile
  const int g0  = blockIdx.x * 64;
  const int b   = g0 >> 11;
  const int n0  = g0 & (NSEQ - 1);

  // ---- A fragments: 2 rowsets x 16 rows x 256 dims, split bf16 ----
  short8 ahi[2][8], alo[2][8];
#pragma unroll
  for (int rs = 0; rs < 2; ++rs) {
    const float* xb = x + (size_t)(b << 8) * NSEQ + (n0 + rg * 32 + rs * 16 + col);
#pragma unroll
    for (int st = 0; st < 8; ++st) {
      short8 h8, l8;
#pragma unroll
      for (int j = 0; j < 8; ++j) {
        float v = xb[(size_t)(st * 32 + kg * 8 + j) * NSEQ];
        unsigned short hh, ll2;
        bsplit(v, hh, ll2);
        h8[j] = (short)hh; l8[j] = (short)ll2;
      }
      ahi[rs][st] = h8; alo[rs][st] = l8;
    }
  }

  // ---- prologue: stage tile 0 ----
#pragma unroll
  for (int s = 0; s < 8; ++s)
    gload_lds16(cbsplit + s * 8192 + wid * 1024 + (l << 4),
                (char*)&tiles[0][0] + s * 8192 + wid * 1024);
  __syncthreads();

  float v1[2][4], v2[2][4]; int i1[2][4];
#pragma unroll
  for (int rs = 0; rs < 2; ++rs)
#pragma unroll
    for (int r = 0; r < 4; ++r) { v1[rs][r] = FLT_MAX; v2[rs][r] = FLT_MAX; i1[rs][r] = 0; }

  int cur = 0;
  for (int ti = 0; ti < NTILE; ++ti) {
    if (ti + 1 < NTILE) {
      const char* src = cbsplit + (size_t)(ti + 1) * 65536;
#pragma unroll
      for (int s = 0; s < 8; ++s)
        gload_lds16(src + s * 8192 + wid * 1024 + (l << 4),
                    (char*)&tiles[cur ^ 1][0] + s * 8192 + wid * 1024);
    }

    f32x4 acc[2] = {{0, 0, 0, 0}, {0, 0, 0, 0}};
    const char* base = (const char*)&tiles[cur][0] + (ch << 11) + (l << 4);
    __builtin_amdgcn_s_setprio(1);
#pragma unroll
    for (int st = 0; st < 8; ++st) {
      const char* p = base + (st << 13);     // st*8192 + ch*2048
      short8 bh = *(const short8*)p;
      short8 bl = *(const short8*)(p + 1024);
      acc[0] = __builtin_amdgcn_mfma_f32_16x16x32_bf16(ahi[0][st], bh, acc[0], 0, 0, 0);
      acc[1] = __builtin_amdgcn_mfma_f32_16x16x32_bf16(ahi[1][st], bh, acc[1], 0, 0, 0);
      acc[0] = __builtin_amdgcn_mfma_f32_16x16x32_bf16(alo[0][st], bh, acc[0], 0, 0, 0);
      acc[1] = __builtin_amdgcn_mfma_f32_16x16x32_bf16(alo[1][st], bh, acc[1], 0, 0, 0);
      acc[0] = __builtin_amdgcn_mfma_f32_16x16x32_bf16(ahi[0][st], bl, acc[0], 0, 0, 0);
      acc[1] = __builtin_amdgcn_mfma_f32_16x16x32_bf16(ahi[1][st], bl, acc[1], 0, 0, 0);
    }
    __builtin_amdgcn_s_setprio(0);

    // dist = cn - 2*dot; top-2 (ascending k + strict '<' => first occurrence)
    {
      int k = ti * 64 + ch * 16 + col;
      float cn = cn32[k];
#pragma unroll
      for (int rs = 0; rs < 2; ++rs)
#pragma unroll
        for (int r = 0; r < 4; ++r) {
          float dist = fmaf(-2.f, acc[rs][r], cn);
          if (dist < v1[rs][r]) { v2[rs][r] = v1[rs][r]; v1[rs][r] = dist; i1[rs][r] = k; }
          else                  { v2[rs][r] = fminf(v2[rs][r], dist); }
        }
    }
    __syncthreads();
    cur ^= 1;
  }

  // ---- merge top-2 across the 16 col-lanes (bits 0..3 of lane) ----
#pragma unroll
  for (int rs = 0; rs < 2; ++rs)
#pragma unroll
    for (int r = 0; r < 4; ++r) {
      float a1 = v1[rs][r], a2 = v2[rs][r]; int ai = i1[rs][r];
#pragma unroll
      for (int off = 1; off < 16; off <<= 1) {
        float o1 = __shfl_xor(a1, off, 64);
        float o2 = __shfl_xor(a2, off, 64);
        int   oi = __shfl_xor(ai, off, 64);
        if (o1 < a1 || (o1 == a1 && oi < ai)) { a2 = fminf(a1, o2); a1 = o1; ai = oi; }
        else                                  { a2 = fminf(a2, o1); }
      }
      if (col == 0) {
        m1[wid][rs * 16 + kg * 4 + r] = a1;
        m2[wid][rs * 16 + kg * 4 + r] = a2;
        mi[wid][rs * 16 + kg * 4 + r] = ai;
      }
    }
  __syncthreads();

  // ---- merge the 4 ch-waves per row-group; finalize index, flag ----
  if (t < 64) {
    int rgg = t >> 5, lrr = t & 31;
    float a1 = m1[rgg * 4][lrr], a2 = m2[rgg * 4][lrr]; int ai = mi[rgg * 4][lrr];
#pragma unroll
    for (int c = 1; c < 4; ++c) {
      float o1 = m1[rgg * 4 + c][lrr], o2 = m2[rgg * 4 + c][lrr];
      int   oi = mi[rgg * 4 + c][lrr];
      if (o1 < a1 || (o1 == a1 && oi < ai)) { a2 = fminf(a1, o2); a1 = o1; ai = oi; }
      else                                  { a2 = fminf(a2, o1); }
    }
    bool flag = (a2 - a1) < THRESH;
    sIdx[t] = ai;
    idxws[g0 + t] = flag ? -(ai + 1) : ai;
    out[IDXOFF + g0 + t] = (float)ai;
    if (flag) { int p = atomicAdd(rcount, 1); if (p < RCAP) rlist[p] = g0 + t; }
  }
  __syncthreads();

  // ---- gather winning rows into LDS (stride 257 -> conflict-free columns) ----
  float* qt = (float*)&tiles[0][0];
  {
    int r = t >> 3, seg = t & 7;
    const float4* cp = (const float4*)(cb + (size_t)sIdx[r] * DIM + seg * 32);
#pragma unroll
    for (int i = 0; i < 8; ++i) {
      float4 v = cp[i];
      int d = seg * 32 + i * 4;
      qt[r * 257 + d]     = v.x;
      qt[r * 257 + d + 1] = v.y;
      qt[r * 257 + d + 2] = v.z;
      qt[r * 257 + d + 3] = v.w;
    }
  }
  __syncthreads();

  // ---- quantized write (256B coalesced) + commitment loss ----
  float lsum = 0.f;
  {
    int r = t & 63, part = t >> 6;
    const float* xp = x   + (size_t)((b << 8) + part * 32) * NSEQ + n0 + r;
    float*       op = out + (size_t)((b << 8) + part * 32) * NSEQ + n0 + r;
#pragma unroll
    for (int i = 0; i < 32; ++i) {
      float qv = qt[r * 257 + part * 32 + i];
      float xv = xp[(size_t)i * NSEQ];
      op[(size_t)i * NSEQ] = qv;
      float dx = qv - xv;
      lsum = fmaf(dx, dx, lsum);
    }
  }
#pragma unroll
  for (int off = 32; off > 0; off >>= 1) lsum += __shfl_xor(lsum, off, 64);
  if (l == 0) wl[wid] = lsum;
  __syncthreads();
  if (t == 0) {
    float s = 0.f;
#pragma unroll
    for (int w = 0; w < 8; ++w) s += wl[w];
    atomicAdd(out + LOSS_OFF, s * LOSS_SCALE);
  }
}

// -------- rescreen: exact f64 argmin for flagged rows, fix outputs ---------
__global__ __launch_bounds__(256) void fsq_rescreen(
    const float* __restrict__ x, const float* __restrict__ cb,
    const double* __restrict__ cn64, const int* __restrict__ rcount,
    const int* __restrict__ rlist, const int* __restrict__ idxws,
    float* __restrict__ out) {
  __shared__ float  xrow[DIM];
  __shared__ double rv[4];
  __shared__ int    ri[4];
  __shared__ int    sBi;
  __shared__ float  dl[4];

  const int t    = threadIdx.x;
  const int lane = t & 63;
  const int wv   = t >> 6;
  int cnt = *rcount;
  if (cnt > RCAP) cnt = RCAP;
  if (cnt < 0) cnt = 0;

  for (int i = blockIdx.x; i < cnt; i += gridDim.x) {
    const int row = rlist[i] & 16383;
    const int b   = row >> 11;
    const int n   = row & (NSEQ - 1);
    xrow[t] = x[((size_t)(b << 8) + t) * NSEQ + n];
    __syncthreads();

    double best = DBL_MAX;
    int    bi   = 0;
    const float4* xr = reinterpret_cast<const float4*>(&xrow[0]);
#pragma unroll 1
    for (int c = 0; c < 16; ++c) {
      int k = t + (c << 8);
      const float4* cp = reinterpret_cast<const float4*>(cb + (size_t)k * DIM);
      double dot = 0.0;
#pragma unroll 4
      for (int d4 = 0; d4 < DIM / 4; ++d4) {
        float4 cv = cp[d4];
        float4 xv = xr[d4];
        dot += (double)xv.x * cv.x + (double)xv.y * cv.y +
               (double)xv.z * cv.z + (double)xv.w * cv.w;
      }
      double dist = cn64[k] - 2.0 * dot;
      if (dist < best || (dist == best && k < bi)) { best = dist; bi = k; }
    }
#pragma unroll
    for (int off = 1; off < 64; off <<= 1) {
      double ob = __shfl_xor(best, off, 64);
      int    oi = __shfl_xor(bi, off, 64);
      if (ob < best || (ob == best && oi < bi)) { best = ob; bi = oi; }
    }
    if (lane == 0) { rv[wv] = best; ri[wv] = bi; }
    __syncthreads();
    if (t == 0) {
      double bb = rv[0]; int ii = ri[0];
#pragma unroll
      for (int w = 1; w < 4; ++w)
        if (rv[w] < bb || (rv[w] == bb && ri[w] < ii)) { bb = rv[w]; ii = ri[w]; }
      sBi = ii;
    }
    __syncthreads();

    int enc = idxws[row];
    int old = (enc < 0) ? -(enc + 1) : enc;
    int nw  = sBi;
    if (nw != old) {
      if (t == 0) out[IDXOFF + row] = (float)nw;
      float qn = cb[(size_t)nw  * DIM + t];
      float qo = cb[(size_t)old * DIM + t];
      float xv = xrow[t];
      out[((size_t)(b << 8) + t) * NSEQ + n] = qn;
      float d1 = qn - xv, d0 = qo - xv;
      float delta = d1 * d1 - d0 * d0;
#pragma unroll
      for (int off = 32; off > 0; off >>= 1) delta += __shfl_xor(delta, off, 64);
      if (lane == 0) dl[wv] = delta;
      __syncthreads();
      if (t == 0) atomicAdd(out + LOSS_OFF, (dl[0] + dl[1] + dl[2] + dl[3]) * LOSS_SCALE);
    }
    __syncthreads();
  }
}

extern "C" void kernel_launch(void* const* d_in, const int* in_sizes, int n_in,
                              void* d_out, int out_size, void* d_ws, size_t ws_size,
                              hipStream_t stream) {
  const float* x  = (const float*)d_in[0];   // [8, 256, 2048]
  const float* cb = (const float*)d_in[1];   // [4096, 256]
  float* out = (float*)d_out;

  char* wsb = (char*)d_ws;
  int*    rcount = (int*)(wsb + 8);
  float*  cn32   = (float*)(wsb + 4096);                          // 16 KB
  double* cn64   = (double*)(wsb + 4096 + 16384);                 // 32 KB
  int*    idxws  = (int*)(wsb + 4096 + 16384 + 32768);            // 64 KB
  int*    rlist  = (int*)(wsb + 4096 + 16384 + 32768 + 65536);    // 4 KB
  char*   cbsplit = wsb + 131072;                                 // 4 MB

  fsq_prep<<<528, 256, 0, stream>>>(cb, cbsplit, cn32, cn64, rcount, out);
  fsq_score<<<256, 512, 0, stream>>>(x, cb, cbsplit, cn32, idxws, rcount, rlist, out);
  fsq_rescreen<<<64, 256, 0, stream>>>(x, cb, cn64, rcount, rlist, idxws, out);
}

// Round 7
// 271.520 us; speedup vs baseline: 1.2383x; 1.2383x over previous
//
#include <hip/hip_runtime.h>
#include <float.h>

#define DIM      256
#define KCODES   4096
#define NSEQ     2048
#define IDXOFF   4194304
#define LOSS_OFF 4210688
#define NTILE    64
#define THRESH   1.0e-3f
#define RCAP     512
#define LOSS_SCALE (0.25f / 4194304.0f)

typedef __attribute__((ext_vector_type(8))) short short8;
typedef __attribute__((ext_vector_type(4))) float f32x4;

// f32 -> bf16(hi) + bf16(lo) split, RNE
__device__ __forceinline__ void bsplit(float x, unsigned short& hi, unsigned short& lo) {
  union { float f; unsigned u; } a; a.f = x;
  unsigned r = a.u + 0x7FFFu + ((a.u >> 16) & 1u);
  hi = (unsigned short)(r >> 16);
  union { unsigned u; float f; } h; h.u = ((unsigned)hi) << 16;
  float res = x - h.f;
  union { float f; unsigned u; } b2; b2.f = res;
  unsigned r2 = b2.u + 0x7FFFu + ((b2.u >> 16) & 1u);
  lo = (unsigned short)(r2 >> 16);
}

__device__ __forceinline__ void gload_lds16(const void* g, void* l) {
  __builtin_amdgcn_global_load_lds(
      (const __attribute__((address_space(1))) unsigned*)g,
      (__attribute__((address_space(3))) unsigned*)l, 16, 0, 0);
}

// counted-vmcnt phase boundary: wait N oldest loads, barrier, pin scheduling
#define PHASE_WAIT4 { asm volatile("s_waitcnt vmcnt(4)" ::: "memory"); \
                      __builtin_amdgcn_s_barrier(); \
                      __builtin_amdgcn_sched_barrier(0); }
#define PHASE_WAIT0 { asm volatile("s_waitcnt vmcnt(0)" ::: "memory"); \
                      __builtin_amdgcn_s_barrier(); \
                      __builtin_amdgcn_sched_barrier(0); }

// ---- prep: blocks 0..511 split codebook into plane-separated fragment order;
//      blocks 512..527 norms. cbsplit per tile ti (64KB): hi plane 32KB then lo.
//      hi byte = (st*4+ch)*1024 + l*16, l = kg*16+col
//      holds cb[ti*64 + ch*16 + col][st*32 + kg*8 + j], j=0..7
__global__ __launch_bounds__(256) void fsq_prep(const float* __restrict__ cb,
                                                char* __restrict__ cbsplit,
                                                float* __restrict__ cn32,
                                                double* __restrict__ cn64,
                                                int* __restrict__ rcount,
                                                float* __restrict__ out) {
  const int bid = blockIdx.x;
  const int t   = threadIdx.x;
  if (bid < 512) {
    int tid = bid * 256 + t;           // 0..131071
    int ti  = tid >> 11;
    int c   = tid & 2047;              // (st*4+ch)*64 + l
    int st  = c >> 8;
    int ch  = (c >> 6) & 3;
    int l   = c & 63;
    int kg  = l >> 4, col = l & 15;
    int code  = ti * 64 + ch * 16 + col;
    int dbase = st * 32 + kg * 8;
    const float4* p = (const float4*)(cb + (size_t)code * DIM + dbase);
    float4 aa = p[0], bb = p[1];
    float vv[8] = {aa.x, aa.y, aa.z, aa.w, bb.x, bb.y, bb.z, bb.w};
    short8 h8, l8;
#pragma unroll
    for (int j = 0; j < 8; ++j) {
      unsigned short hh, lo2;
      bsplit(vv[j], hh, lo2);
      h8[j] = (short)hh; l8[j] = (short)lo2;
    }
    char* tb = cbsplit + (size_t)ti * 65536 + c * 16;
    *(short8*)tb = h8;                 // hi plane
    *(short8*)(tb + 32768) = l8;       // lo plane
  } else {
    int code = (bid - 512) * 256 + t;
    const float4* c4 = reinterpret_cast<const float4*>(cb + (size_t)code * DIM);
    double s = 0.0;
#pragma unroll 8
    for (int i = 0; i < DIM / 4; ++i) {
      float4 v = c4[i];
      s += (double)v.x * v.x + (double)v.y * v.y + (double)v.z * v.z + (double)v.w * v.w;
    }
    cn32[code] = (float)s;
    cn64[code] = s;
    if (code == 0) { *rcount = 0; out[LOSS_OFF] = 0.0f; }
  }
}

// ---- main: MFMA screen, counted-vmcnt hi/lo pipeline, fused output ----
__global__ __launch_bounds__(512, 1) void fsq_score(
    const float* __restrict__ x, const float* __restrict__ cb,
    const char* __restrict__ cbsplit, const float* __restrict__ cn32,
    int* __restrict__ idxws, int* __restrict__ rcount, int* __restrict__ rlist,
    float* __restrict__ out) {
  // lds: hi slots at 0,32768; lo slots at 65536,98304
  __shared__ __align__(16) char lds[131072];
  __shared__ float m1[8][32], m2[8][32];
  __shared__ int   mi[8][32];
  __shared__ int   sIdx[64];
  __shared__ float wl[8];

  const int t   = threadIdx.x;
  const int wid = t >> 6;
  const int l   = t & 63;
  const int col = l & 15;
  const int kg  = l >> 4;
  const int rg  = wid >> 2;      // 0..1 : 32-row group
  const int ch  = wid & 3;       // 0..3 : 16-code slice of each tile
  const int g0  = blockIdx.x * 64;
  const int b   = g0 >> 11;
  const int n0  = g0 & (NSEQ - 1);

  // ---- A fragments: 2 rowsets x 16 rows x 256 dims, split bf16 (in regs) ----
  short8 ahi[2][8], alo[2][8];
#pragma unroll
  for (int rs = 0; rs < 2; ++rs) {
    const float* xb = x + (size_t)(b << 8) * NSEQ + (n0 + rg * 32 + rs * 16 + col);
#pragma unroll
    for (int st = 0; st < 8; ++st) {
      short8 h8, l8;
#pragma unroll
      for (int j = 0; j < 8; ++j) {
        float v = xb[(size_t)(st * 32 + kg * 8 + j) * NSEQ];
        unsigned short hh, ll2;
        bsplit(v, hh, ll2);
        h8[j] = (short)hh; l8[j] = (short)ll2;
      }
      ahi[rs][st] = h8; alo[rs][st] = l8;
    }
  }

  // staging: wave wid covers bytes [wid*4K, wid*4K+4K) of the 32KB plane
#define ISSUE(ti_, hl_, slot_)                                                  \
  {                                                                             \
    const char* src_ = cbsplit + (size_t)(ti_) * 65536 + (hl_) * 32768 + wid * 4096; \
    char* dst_ = lds + (hl_) * 65536 + (slot_) * 32768 + wid * 4096;            \
    _Pragma("unroll")                                                           \
    for (int j_ = 0; j_ < 4; ++j_)                                              \
      gload_lds16(src_ + j_ * 1024 + (l << 4), dst_ + j_ * 1024);               \
  }

  // prologue: hi(0), lo(0) in flight (8 per wave)
  ISSUE(0, 0, 0)
  ISSUE(0, 1, 0)

  float v1[2][4], v2[2][4]; int i1[2][4];
#pragma unroll
  for (int rs = 0; rs < 2; ++rs)
#pragma unroll
    for (int r = 0; r < 4; ++r) { v1[rs][r] = FLT_MAX; v2[rs][r] = FLT_MAX; i1[rs][r] = 0; }

  // invariant entering iter ti: outstanding = {hi(ti):4, lo(ti):4}
  for (int ti = 0; ti < NTILE - 1; ++ti) {
    const int cur = ti & 1;
    f32x4 acc0 = {0, 0, 0, 0}, acc1 = {0, 0, 0, 0};

    // phase H: wait hi(ti) (lo(ti) stays in flight), prefetch hi(ti+1)
    PHASE_WAIT4
    ISSUE(ti + 1, 0, cur ^ 1)
    {
      const char* bh_base = lds + cur * 32768 + (ch << 10) + (l << 4);
      __builtin_amdgcn_s_setprio(1);
#pragma unroll
      for (int st = 0; st < 8; ++st) {
        short8 bh = *(const short8*)(bh_base + (st << 12));
        acc0 = __builtin_amdgcn_mfma_f32_16x16x32_bf16(ahi[0][st], bh, acc0, 0, 0, 0);
        acc1 = __builtin_amdgcn_mfma_f32_16x16x32_bf16(ahi[1][st], bh, acc1, 0, 0, 0);
        acc0 = __builtin_amdgcn_mfma_f32_16x16x32_bf16(alo[0][st], bh, acc0, 0, 0, 0);
        acc1 = __builtin_amdgcn_mfma_f32_16x16x32_bf16(alo[1][st], bh, acc1, 0, 0, 0);
      }
      __builtin_amdgcn_s_setprio(0);
    }

    // phase L: wait lo(ti) (hi(ti+1) stays in flight), prefetch lo(ti+1)
    PHASE_WAIT4
    ISSUE(ti + 1, 1, cur ^ 1)
    {
      const char* bl_base = lds + 65536 + cur * 32768 + (ch << 10) + (l << 4);
      __builtin_amdgcn_s_setprio(1);
#pragma unroll
      for (int st = 0; st < 8; ++st) {
        short8 bl = *(const short8*)(bl_base + (st << 12));
        acc0 = __builtin_amdgcn_mfma_f32_16x16x32_bf16(ahi[0][st], bl, acc0, 0, 0, 0);
        acc1 = __builtin_amdgcn_mfma_f32_16x16x32_bf16(ahi[1][st], bl, acc1, 0, 0, 0);
      }
      __builtin_amdgcn_s_setprio(0);
    }

    // dist + top-2 (ascending k + strict '<' => first occurrence)
    {
      int k = ti * 64 + ch * 16 + col;
      float cn = cn32[k];
      f32x4 av[2] = {acc0, acc1};
#pragma unroll
      for (int rs = 0; rs < 2; ++rs)
#pragma unroll
        for (int r = 0; r < 4; ++r) {
          float dist = fmaf(-2.f, av[rs][r], cn);
          if (dist < v1[rs][r]) { v2[rs][r] = v1[rs][r]; v1[rs][r] = dist; i1[rs][r] = k; }
          else                  { v2[rs][r] = fminf(v2[rs][r], dist); }
        }
    }
  }

  // tail tile 63
  {
    const int cur = (NTILE - 1) & 1;
    f32x4 acc0 = {0, 0, 0, 0}, acc1 = {0, 0, 0, 0};
    PHASE_WAIT4   // hi(63) ready, lo(63) in flight
    {
      const char* bh_base = lds + cur * 32768 + (ch << 10) + (l << 4);
#pragma unroll
      for (int st = 0; st < 8; ++st) {
        short8 bh = *(const short8*)(bh_base + (st << 12));
        acc0 = __builtin_amdgcn_mfma_f32_16x16x32_bf16(ahi[0][st], bh, acc0, 0, 0, 0);
        acc1 = __builtin_amdgcn_mfma_f32_16x16x32_bf16(ahi[1][st], bh, acc1, 0, 0, 0);
        acc0 = __builtin_amdgcn_mfma_f32_16x16x32_bf16(alo[0][st], bh, acc0, 0, 0, 0);
        acc1 = __builtin_amdgcn_mfma_f32_16x16x32_bf16(alo[1][st], bh, acc1, 0, 0, 0);
      }
    }
    PHASE_WAIT0   // lo(63) ready
    {
      const char* bl_base = lds + 65536 + cur * 32768 + (ch << 10) + (l << 4);
#pragma unroll
      for (int st = 0; st < 8; ++st) {
        short8 bl = *(const short8*)(bl_base + (st << 12));
        acc0 = __builtin_amdgcn_mfma_f32_16x16x32_bf16(ahi[0][st], bl, acc0, 0, 0, 0);
        acc1 = __builtin_amdgcn_mfma_f32_16x16x32_bf16(ahi[1][st], bl, acc1, 0, 0, 0);
      }
    }
    int k = (NTILE - 1) * 64 + ch * 16 + col;
    float cn = cn32[k];
    f32x4 av[2] = {acc0, acc1};
#pragma unroll
    for (int rs = 0; rs < 2; ++rs)
#pragma unroll
      for (int r = 0; r < 4; ++r) {
        float dist = fmaf(-2.f, av[rs][r], cn);
        if (dist < v1[rs][r]) { v2[rs][r] = v1[rs][r]; v1[rs][r] = dist; i1[rs][r] = k; }
        else                  { v2[rs][r] = fminf(v2[rs][r], dist); }
      }
  }

  // ---- merge top-2 across the 16 col-lanes ----
#pragma unroll
  for (int rs = 0; rs < 2; ++rs)
#pragma unroll
    for (int r = 0; r < 4; ++r) {
      float a1 = v1[rs][r], a2 = v2[rs][r]; int ai = i1[rs][r];
#pragma unroll
      for (int off = 1; off < 16; off <<= 1) {
        float o1 = __shfl_xor(a1, off, 64);
        float o2 = __shfl_xor(a2, off, 64);
        int   oi = __shfl_xor(ai, off, 64);
        if (o1 < a1 || (o1 == a1 && oi < ai)) { a2 = fminf(a1, o2); a1 = o1; ai = oi; }
        else                                  { a2 = fminf(a2, o1); }
      }
      if (col == 0) {
        m1[wid][rs * 16 + kg * 4 + r] = a1;
        m2[wid][rs * 16 + kg * 4 + r] = a2;
        mi[wid][rs * 16 + kg * 4 + r] = ai;
      }
    }
  __syncthreads();

  // ---- merge the 4 ch-waves per row-group; finalize index, flag ----
  if (t < 64) {
    int rgg = t >> 5, lrr = t & 31;
    float a1 = m1[rgg * 4][lrr], a2 = m2[rgg * 4][lrr]; int ai = mi[rgg * 4][lrr];
#pragma unroll
    for (int c = 1; c < 4; ++c) {
      float o1 = m1[rgg * 4 + c][lrr], o2 = m2[rgg * 4 + c][lrr];
      int   oi = mi[rgg * 4 + c][lrr];
      if (o1 < a1 || (o1 == a1 && oi < ai)) { a2 = fminf(a1, o2); a1 = o1; ai = oi; }
      else                                  { a2 = fminf(a2, o1); }
    }
    bool flag = (a2 - a1) < THRESH;
    sIdx[t] = ai;
    idxws[g0 + t] = flag ? -(ai + 1) : ai;
    out[IDXOFF + g0 + t] = (float)ai;
    if (flag) { int p = atomicAdd(rcount, 1); if (p < RCAP) rlist[p] = g0 + t; }
  }
  __syncthreads();

  // ---- gather winning rows into LDS (stride 257 -> conflict-free columns) ----
  float* qt = (float*)lds;
  {
    int r = t >> 3, seg = t & 7;
    const float4* cp = (const float4*)(cb + (size_t)sIdx[r] * DIM + seg * 32);
#pragma unroll
    for (int i = 0; i < 8; ++i) {
      float4 v = cp[i];
      int d = seg * 32 + i * 4;
      qt[r * 257 + d]     = v.x;
      qt[r * 257 + d + 1] = v.y;
      qt[r * 257 + d + 2] = v.z;
      qt[r * 257 + d + 3] = v.w;
    }
  }
  __syncthreads();

  // ---- quantized write (256B coalesced) + commitment loss ----
  float lsum = 0.f;
  {
    int r = t & 63, part = t >> 6;
    const float* xp = x   + (size_t)((b << 8) + part * 32) * NSEQ + n0 + r;
    float*       op = out + (size_t)((b << 8) + part * 32) * NSEQ + n0 + r;
#pragma unroll
    for (int i = 0; i < 32; ++i) {
      float qv = qt[r * 257 + part * 32 + i];
      float xv = xp[(size_t)i * NSEQ];
      op[(size_t)i * NSEQ] = qv;
      float dx = qv - xv;
      lsum = fmaf(dx, dx, lsum);
    }
  }
#pragma unroll
  for (int off = 32; off > 0; off >>= 1) lsum += __shfl_xor(lsum, off, 64);
  if (l == 0) wl[wid] = lsum;
  __syncthreads();
  if (t == 0) {
    float s = 0.f;
#pragma unroll
    for (int w = 0; w < 8; ++w) s += wl[w];
    atomicAdd(out + LOSS_OFF, s * LOSS_SCALE);
  }
}

// ---- rescreen stage A: 64 blocks x 64-code slices; codebook read once total.
//      per (flagged row, slice): best f64 (dist, idx) -> cand[row][slice]
__global__ __launch_bounds__(256) void fsq_rescr_a(
    const float* __restrict__ x, const float* __restrict__ cb,
    const double* __restrict__ cn64, const int* __restrict__ rcount,
    const int* __restrict__ rlist, double2* __restrict__ cand) {
  __shared__ float cbs[64][260];   // +4 pad: 16B-aligned rows, mild conflicts ok
  __shared__ float xr[4][DIM];

  int cnt = *rcount;
  if (cnt > RCAP) cnt = RCAP;
  if (cnt <= 0) return;

  const int t    = threadIdx.x;
  const int bid  = blockIdx.x;       // codes [bid*64, bid*64+64)
  const int w    = t >> 6;
  const int lane = t & 63;

  // stage the 64-code slice (f32)
  {
    int r = t >> 2, q = t & 3;
    const float4* cp = (const float4*)(cb + (size_t)(bid * 64 + r) * DIM + q * 64);
#pragma unroll
    for (int j = 0; j < 16; ++j) {
      float4 v = cp[j];
      int d = q * 64 + j * 4;
      cbs[r][d]     = v.x;
      cbs[r][d + 1] = v.y;
      cbs[r][d + 2] = v.z;
      cbs[r][d + 3] = v.w;
    }
  }
  const double cn = cn64[bid * 64 + lane];

  const int nit = (cnt + 3) >> 2;
  for (int it = 0; it < nit; ++it) {
    __syncthreads();   // cbs ready (it=0) / xr reuse safe (it>0)
    {
      int rr = it * 4 + w;
      if (rr < cnt) {
        int row = rlist[rr] & 16383;
        int bb = row >> 11, nn = row & (NSEQ - 1);
#pragma unroll
        for (int j = 0; j < 4; ++j) {
          int d = lane * 4 + j;
          xr[w][d] = x[((size_t)(bb << 8) + d) * NSEQ + nn];
        }
      }
    }
    __syncthreads();
    int rr = it * 4 + w;
    if (rr < cnt) {
      double dot = 0.0;
#pragma unroll 8
      for (int d4 = 0; d4 < DIM / 4; ++d4) {
        float4 cv = *(const float4*)&cbs[lane][d4 * 4];
        float4 xv = *(const float4*)&xr[w][d4 * 4];
        dot += (double)xv.x * cv.x + (double)xv.y * cv.y +
               (double)xv.z * cv.z + (double)xv.w * cv.w;
      }
      double best = cn - 2.0 * dot;
      int    bi   = bid * 64 + lane;
#pragma unroll
      for (int off = 1; off < 64; off <<= 1) {
        double ob = __shfl_xor(best, off, 64);
        int    oi = __shfl_xor(bi, off, 64);
        if (ob < best || (ob == best && oi < bi)) { best = ob; bi = oi; }
      }
      if (lane == 0) cand[rr * 64 + bid] = make_double2(best, (double)bi);
    }
  }
}

// ---- rescreen stage B: merge 64 slice-candidates per row; fix changed rows --
__global__ __launch_bounds__(256) void fsq_rescr_b(
    const float* __restrict__ x, const float* __restrict__ cb,
    const int* __restrict__ rcount, const int* __restrict__ rlist,
    const int* __restrict__ idxws, const double2* __restrict__ cand,
    float* __restrict__ out) {
  int cnt = *rcount;
  if (cnt > RCAP) cnt = RCAP;
  if (cnt <= 0) return;

  const int t    = threadIdx.x;
  const int w    = t >> 6;
  const int lane = t & 63;

  for (int rr = w; rr < cnt; rr += 4) {
    int row = rlist[rr] & 16383;
    double2 e = cand[rr * 64 + lane];
    double best = e.x;
    int    bi   = (int)e.y;
#pragma unroll
    for (int off = 1; off < 64; off <<= 1) {
      double ob = __shfl_xor(best, off, 64);
      int    oi = __shfl_xor(bi, off, 64);
      if (ob < best || (ob == best && oi < bi)) { best = ob; bi = oi; }
    }
    int enc = idxws[row];
    int old = (enc < 0) ? -(enc + 1) : enc;
    if (bi != old) {
      int bb = row >> 11, nn = row & (NSEQ - 1);
      if (lane == 0) out[IDXOFF + row] = (float)bi;
      float delta = 0.f;
#pragma unroll
      for (int j = 0; j < 4; ++j) {
        int d = lane * 4 + j;
        float qn = cb[(size_t)bi  * DIM + d];
        float qo = cb[(size_t)old * DIM + d];
        float xv = x[((size_t)(bb << 8) + d) * NSEQ + nn];
        out[((size_t)(bb << 8) + d) * NSEQ + nn] = qn;
        float d1 = qn - xv, d0 = qo - xv;
        delta += d1 * d1 - d0 * d0;
      }
#pragma unroll
      for (int off = 1; off < 64; off <<= 1) delta += __shfl_xor(delta, off, 64);
      if (lane == 0) atomicAdd(out + LOSS_OFF, delta * LOSS_SCALE);
    }
  }
}

extern "C" void kernel_launch(void* const* d_in, const int* in_sizes, int n_in,
                              void* d_out, int out_size, void* d_ws, size_t ws_size,
                              hipStream_t stream) {
  const float* x  = (const float*)d_in[0];   // [8, 256, 2048]
  const float* cb = (const float*)d_in[1];   // [4096, 256]
  float* out = (float*)d_out;

  char* wsb = (char*)d_ws;
  int*     rcount  = (int*)(wsb + 8);
  float*   cn32    = (float*)(wsb + 4096);                        // 16 KB
  double*  cn64    = (double*)(wsb + 4096 + 16384);               // 32 KB
  int*     idxws   = (int*)(wsb + 4096 + 16384 + 32768);          // 64 KB
  int*     rlist   = (int*)(wsb + 4096 + 16384 + 32768 + 65536);  // 2 KB
  char*    cbsplit = wsb + 131072;                                // 4 MB
  double2* cand    = (double2*)(wsb + 131072 + 4194304);          // 512 KB

  fsq_prep<<<528, 256, 0, stream>>>(cb, cbsplit, cn32, cn64, rcount, out);
  fsq_score<<<256, 512, 0, stream>>>(x, cb, cbsplit, cn32, idxws, rcount, rlist, out);
  fsq_rescr_a<<<64, 256, 0, stream>>>(x, cb, cn64, rcount, rlist, cand);
  fsq_rescr_b<<<1, 256, 0, stream>>>(x, cb, rcount, rlist, idxws, cand, out);
}

// Round 9
// 268.761 us; speedup vs baseline: 1.2510x; 1.0103x over previous
//
#include <hip/hip_runtime.h>
#include <float.h>

#define DIM      256
#define KCODES   4096
#define NSEQ     2048
#define IDXOFF   4194304
#define LOSS_OFF 4210688
#define NTILE    64
#define THRESH   1.0e-3f
#define RCAP     512
#define LOSS_SCALE (0.25f / 4194304.0f)

typedef __attribute__((ext_vector_type(8))) short short8;
typedef __attribute__((ext_vector_type(4))) float f32x4;

// f32 -> bf16(hi) + bf16(lo) split, RNE
__device__ __forceinline__ void bsplit(float x, unsigned short& hi, unsigned short& lo) {
  union { float f; unsigned u; } a; a.f = x;
  unsigned r = a.u + 0x7FFFu + ((a.u >> 16) & 1u);
  hi = (unsigned short)(r >> 16);
  union { unsigned u; float f; } h; h.u = ((unsigned)hi) << 16;
  float res = x - h.f;
  union { float f; unsigned u; } b2; b2.f = res;
  unsigned r2 = b2.u + 0x7FFFu + ((b2.u >> 16) & 1u);
  lo = (unsigned short)(r2 >> 16);
}

__device__ __forceinline__ void gload_lds16(const void* g, void* l) {
  __builtin_amdgcn_global_load_lds(
      (const __attribute__((address_space(1))) unsigned*)g,
      (__attribute__((address_space(3))) unsigned*)l, 16, 0, 0);
}

// counted-vmcnt phase boundary: wait N oldest loads, barrier, pin scheduling
#define PHASE_WAIT4 { asm volatile("s_waitcnt vmcnt(4)" ::: "memory"); \
                      __builtin_amdgcn_s_barrier(); \
                      __builtin_amdgcn_sched_barrier(0); }
#define PHASE_WAIT0 { asm volatile("s_waitcnt vmcnt(0)" ::: "memory"); \
                      __builtin_amdgcn_s_barrier(); \
                      __builtin_amdgcn_sched_barrier(0); }

// ---- prep: blocks 0..511 split codebook into plane-separated fragment order;
//      blocks 512..527 norms. cbsplit per tile ti (64KB): hi plane 32KB then lo.
//      hi byte = (st*4+ch)*1024 + l*16, l = kg*16+col
//      holds cb[ti*64 + ch*16 + col][st*32 + kg*8 + j], j=0..7
__global__ __launch_bounds__(256) void fsq_prep(const float* __restrict__ cb,
                                                char* __restrict__ cbsplit,
                                                float* __restrict__ cn32,
                                                double* __restrict__ cn64,
                                                int* __restrict__ rcount,
                                                float* __restrict__ out) {
  const int bid = blockIdx.x;
  const int t   = threadIdx.x;
  if (bid < 512) {
    int tid = bid * 256 + t;           // 0..131071
    int ti  = tid >> 11;
    int c   = tid & 2047;              // (st*4+ch)*64 + l
    int st  = c >> 8;
    int ch  = (c >> 6) & 3;
    int l   = c & 63;
    int kg  = l >> 4, col = l & 15;
    int code  = ti * 64 + ch * 16 + col;
    int dbase = st * 32 + kg * 8;
    const float4* p = (const float4*)(cb + (size_t)code * DIM + dbase);
    float4 aa = p[0], bb = p[1];
    float vv[8] = {aa.x, aa.y, aa.z, aa.w, bb.x, bb.y, bb.z, bb.w};
    short8 h8, l8;
#pragma unroll
    for (int j = 0; j < 8; ++j) {
      unsigned short hh, lo2;
      bsplit(vv[j], hh, lo2);
      h8[j] = (short)hh; l8[j] = (short)lo2;
    }
    char* tb = cbsplit + (size_t)ti * 65536 + c * 16;
    *(short8*)tb = h8;                 // hi plane
    *(short8*)(tb + 32768) = l8;       // lo plane
  } else {
    int code = (bid - 512) * 256 + t;
    const float4* c4 = reinterpret_cast<const float4*>(cb + (size_t)code * DIM);
    double s = 0.0;
#pragma unroll 8
    for (int i = 0; i < DIM / 4; ++i) {
      float4 v = c4[i];
      s += (double)v.x * v.x + (double)v.y * v.y + (double)v.z * v.z + (double)v.w * v.w;
    }
    cn32[code] = (float)s;
    cn64[code] = s;
    if (code == 0) { *rcount = 0; out[LOSS_OFF] = 0.0f; }
  }
}

// ---- main: MFMA screen, counted-vmcnt hi/lo pipeline, fused output ----
// amdgpu_waves_per_eu(2,2): LDS (131KB) forces 1 block/CU = 2 waves/SIMD;
// cap allocator occupancy target at 2 -> 256-VGPR budget, kills the ~50-reg
// spill (r6/r7: VGPR=128 + 30MB scratch WRITE traffic).
__global__ __launch_bounds__(512)
__attribute__((amdgpu_waves_per_eu(2, 2))) void fsq_score(
    const float* __restrict__ x, const float* __restrict__ cb,
    const char* __restrict__ cbsplit, const float* __restrict__ cn32,
    int* __restrict__ idxws, int* __restrict__ rcount, int* __restrict__ rlist,
    float* __restrict__ out) {
  // lds: hi slots at 0,32768; lo slots at 65536,98304
  __shared__ __align__(16) char lds[131072];
  __shared__ float m1[8][32], m2[8][32];
  __shared__ int   mi[8][32];
  __shared__ int   sIdx[64];
  __shared__ float wl[8];

  const int t   = threadIdx.x;
  const int wid = t >> 6;
  const int l   = t & 63;
  const int col = l & 15;
  const int kg  = l >> 4;
  const int rg  = wid >> 2;      // 0..1 : 32-row group
  const int ch  = wid & 3;       // 0..3 : 16-code slice of each tile
  const int g0  = blockIdx.x * 64;
  const int b   = g0 >> 11;
  const int n0  = g0 & (NSEQ - 1);

  // ---- A fragments: 2 rowsets x 16 rows x 256 dims, split bf16 (in regs) ----
  short8 ahi[2][8], alo[2][8];
#pragma unroll
  for (int rs = 0; rs < 2; ++rs) {
    const float* xb = x + (size_t)(b << 8) * NSEQ + (n0 + rg * 32 + rs * 16 + col);
#pragma unroll
    for (int st = 0; st < 8; ++st) {
      short8 h8, l8;
#pragma unroll
      for (int j = 0; j < 8; ++j) {
        float v = xb[(size_t)(st * 32 + kg * 8 + j) * NSEQ];
        unsigned short hh, ll2;
        bsplit(v, hh, ll2);
        h8[j] = (short)hh; l8[j] = (short)ll2;
      }
      ahi[rs][st] = h8; alo[rs][st] = l8;
    }
  }

  // staging: wave wid covers bytes [wid*4K, wid*4K+4K) of the 32KB plane
#define ISSUE(ti_, hl_, slot_)                                                  \
  {                                                                             \
    const char* src_ = cbsplit + (size_t)(ti_) * 65536 + (hl_) * 32768 + wid * 4096; \
    char* dst_ = lds + (hl_) * 65536 + (slot_) * 32768 + wid * 4096;            \
    _Pragma("unroll")                                                           \
    for (int j_ = 0; j_ < 4; ++j_)                                              \
      gload_lds16(src_ + j_ * 1024 + (l << 4), dst_ + j_ * 1024);               \
  }

  // prologue: hi(0), lo(0) in flight (8 per wave)
  ISSUE(0, 0, 0)
  ISSUE(0, 1, 0)

  float v1[2][4], v2[2][4]; int i1[2][4];
#pragma unroll
  for (int rs = 0; rs < 2; ++rs)
#pragma unroll
    for (int r = 0; r < 4; ++r) { v1[rs][r] = FLT_MAX; v2[rs][r] = FLT_MAX; i1[rs][r] = 0; }

  // invariant entering iter ti: outstanding = {hi(ti):4, lo(ti):4}
  for (int ti = 0; ti < NTILE - 1; ++ti) {
    const int cur = ti & 1;
    f32x4 acc0 = {0, 0, 0, 0}, acc1 = {0, 0, 0, 0};

    // phase H: wait hi(ti) (lo(ti) stays in flight), prefetch hi(ti+1)
    PHASE_WAIT4
    ISSUE(ti + 1, 0, cur ^ 1)
    {
      const char* bh_base = lds + cur * 32768 + (ch << 10) + (l << 4);
      __builtin_amdgcn_s_setprio(1);
#pragma unroll
      for (int st = 0; st < 8; ++st) {
        short8 bh = *(const short8*)(bh_base + (st << 12));
        acc0 = __builtin_amdgcn_mfma_f32_16x16x32_bf16(ahi[0][st], bh, acc0, 0, 0, 0);
        acc1 = __builtin_amdgcn_mfma_f32_16x16x32_bf16(ahi[1][st], bh, acc1, 0, 0, 0);
        acc0 = __builtin_amdgcn_mfma_f32_16x16x32_bf16(alo[0][st], bh, acc0, 0, 0, 0);
        acc1 = __builtin_amdgcn_mfma_f32_16x16x32_bf16(alo[1][st], bh, acc1, 0, 0, 0);
      }
      __builtin_amdgcn_s_setprio(0);
    }

    // phase L: wait lo(ti) (hi(ti+1) stays in flight), prefetch lo(ti+1)
    PHASE_WAIT4
    ISSUE(ti + 1, 1, cur ^ 1)
    {
      const char* bl_base = lds + 65536 + cur * 32768 + (ch << 10) + (l << 4);
      __builtin_amdgcn_s_setprio(1);
#pragma unroll
      for (int st = 0; st < 8; ++st) {
        short8 bl = *(const short8*)(bl_base + (st << 12));
        acc0 = __builtin_amdgcn_mfma_f32_16x16x32_bf16(ahi[0][st], bl, acc0, 0, 0, 0);
        acc1 = __builtin_amdgcn_mfma_f32_16x16x32_bf16(ahi[1][st], bl, acc1, 0, 0, 0);
      }
      __builtin_amdgcn_s_setprio(0);
    }

    // dist + top-2 (ascending k + strict '<' => first occurrence)
    {
      int k = ti * 64 + ch * 16 + col;
      float cn = cn32[k];
      f32x4 av[2] = {acc0, acc1};
#pragma unroll
      for (int rs = 0; rs < 2; ++rs)
#pragma unroll
        for (int r = 0; r < 4; ++r) {
          float dist = fmaf(-2.f, av[rs][r], cn);
          if (dist < v1[rs][r]) { v2[rs][r] = v1[rs][r]; v1[rs][r] = dist; i1[rs][r] = k; }
          else                  { v2[rs][r] = fminf(v2[rs][r], dist); }
        }
    }
  }

  // tail tile 63
  {
    const int cur = (NTILE - 1) & 1;
    f32x4 acc0 = {0, 0, 0, 0}, acc1 = {0, 0, 0, 0};
    PHASE_WAIT4   // hi(63) ready, lo(63) in flight
    {
      const char* bh_base = lds + cur * 32768 + (ch << 10) + (l << 4);
#pragma unroll
      for (int st = 0; st < 8; ++st) {
        short8 bh = *(const short8*)(bh_base + (st << 12));
        acc0 = __builtin_amdgcn_mfma_f32_16x16x32_bf16(ahi[0][st], bh, acc0, 0, 0, 0);
        acc1 = __builtin_amdgcn_mfma_f32_16x16x32_bf16(ahi[1][st], bh, acc1, 0, 0, 0);
        acc0 = __builtin_amdgcn_mfma_f32_16x16x32_bf16(alo[0][st], bh, acc0, 0, 0, 0);
        acc1 = __builtin_amdgcn_mfma_f32_16x16x32_bf16(alo[1][st], bh, acc1, 0, 0, 0);
      }
    }
    PHASE_WAIT0   // lo(63) ready
    {
      const char* bl_base = lds + 65536 + cur * 32768 + (ch << 10) + (l << 4);
#pragma unroll
      for (int st = 0; st < 8; ++st) {
        short8 bl = *(const short8*)(bl_base + (st << 12));
        acc0 = __builtin_amdgcn_mfma_f32_16x16x32_bf16(ahi[0][st], bl, acc0, 0, 0, 0);
        acc1 = __builtin_amdgcn_mfma_f32_16x16x32_bf16(ahi[1][st], bl, acc1, 0, 0, 0);
      }
    }
    int k = (NTILE - 1) * 64 + ch * 16 + col;
    float cn = cn32[k];
    f32x4 av[2] = {acc0, acc1};
#pragma unroll
    for (int rs = 0; rs < 2; ++rs)
#pragma unroll
      for (int r = 0; r < 4; ++r) {
        float dist = fmaf(-2.f, av[rs][r], cn);
        if (dist < v1[rs][r]) { v2[rs][r] = v1[rs][r]; v1[rs][r] = dist; i1[rs][r] = k; }
        else                  { v2[rs][r] = fminf(v2[rs][r], dist); }
      }
  }

  // ---- merge top-2 across the 16 col-lanes ----
#pragma unroll
  for (int rs = 0; rs < 2; ++rs)
#pragma unroll
    for (int r = 0; r < 4; ++r) {
      float a1 = v1[rs][r], a2 = v2[rs][r]; int ai = i1[rs][r];
#pragma unroll
      for (int off = 1; off < 16; off <<= 1) {
        float o1 = __shfl_xor(a1, off, 64);
        float o2 = __shfl_xor(a2, off, 64);
        int   oi = __shfl_xor(ai, off, 64);
        if (o1 < a1 || (o1 == a1 && oi < ai)) { a2 = fminf(a1, o2); a1 = o1; ai = oi; }
        else                                  { a2 = fminf(a2, o1); }
      }
      if (col == 0) {
        m1[wid][rs * 16 + kg * 4 + r] = a1;
        m2[wid][rs * 16 + kg * 4 + r] = a2;
        mi[wid][rs * 16 + kg * 4 + r] = ai;
      }
    }
  __syncthreads();

  // ---- merge the 4 ch-waves per row-group; finalize index, flag ----
  if (t < 64) {
    int rgg = t >> 5, lrr = t & 31;
    float a1 = m1[rgg * 4][lrr], a2 = m2[rgg * 4][lrr]; int ai = mi[rgg * 4][lrr];
#pragma unroll
    for (int c = 1; c < 4; ++c) {
      float o1 = m1[rgg * 4 + c][lrr], o2 = m2[rgg * 4 + c][lrr];
      int   oi = mi[rgg * 4 + c][lrr];
      if (o1 < a1 || (o1 == a1 && oi < ai)) { a2 = fminf(a1, o2); a1 = o1; ai = oi; }
      else                                  { a2 = fminf(a2, o1); }
    }
    bool flag = (a2 - a1) < THRESH;
    sIdx[t] = ai;
    idxws[g0 + t] = flag ? -(ai + 1) : ai;
    out[IDXOFF + g0 + t] = (float)ai;
    if (flag) { int p = atomicAdd(rcount, 1); if (p < RCAP) rlist[p] = g0 + t; }
  }
  __syncthreads();

  // ---- gather winning rows into LDS (stride 257 -> conflict-free columns) ----
  float* qt = (float*)lds;
  {
    int r = t >> 3, seg = t & 7;
    const float4* cp = (const float4*)(cb + (size_t)sIdx[r] * DIM + seg * 32);
#pragma unroll
    for (int i = 0; i < 8; ++i) {
      float4 v = cp[i];
      int d = seg * 32 + i * 4;
      qt[r * 257 + d]     = v.x;
      qt[r * 257 + d + 1] = v.y;
      qt[r * 257 + d + 2] = v.z;
      qt[r * 257 + d + 3] = v.w;
    }
  }
  __syncthreads();

  // ---- quantized write (256B coalesced) + commitment loss ----
  float lsum = 0.f;
  {
    int r = t & 63, part = t >> 6;
    const float* xp = x   + (size_t)((b << 8) + part * 32) * NSEQ + n0 + r;
    float*       op = out + (size_t)((b << 8) + part * 32) * NSEQ + n0 + r;
#pragma unroll
    for (int i = 0; i < 32; ++i) {
      float qv = qt[r * 257 + part * 32 + i];
      float xv = xp[(size_t)i * NSEQ];
      op[(size_t)i * NSEQ] = qv;
      float dx = qv - xv;
      lsum = fmaf(dx, dx, lsum);
    }
  }
#pragma unroll
  for (int off = 32; off > 0; off >>= 1) lsum += __shfl_xor(lsum, off, 64);
  if (l == 0) wl[wid] = lsum;
  __syncthreads();
  if (t == 0) {
    float s = 0.f;
#pragma unroll
    for (int w = 0; w < 8; ++w) s += wl[w];
    atomicAdd(out + LOSS_OFF, s * LOSS_SCALE);
  }
}

// ---- rescreen stage A: 64 blocks x 64-code slices; codebook read once total.
//      per (flagged row, slice): best f64 (dist, idx) -> cand[row][slice]
__global__ __launch_bounds__(256) void fsq_rescr_a(
    const float* __restrict__ x, const float* __restrict__ cb,
    const double* __restrict__ cn64, const int* __restrict__ rcount,
    const int* __restrict__ rlist, double2* __restrict__ cand) {
  __shared__ float cbs[64][260];   // +4 pad: 16B-aligned rows, mild conflicts ok
  __shared__ float xr[4][DIM];

  int cnt = *rcount;
  if (cnt > RCAP) cnt = RCAP;
  if (cnt <= 0) return;

  const int t    = threadIdx.x;
  const int bid  = blockIdx.x;       // codes [bid*64, bid*64+64)
  const int w    = t >> 6;
  const int lane = t & 63;

  // stage the 64-code slice (f32)
  {
    int r = t >> 2, q = t & 3;
    const float4* cp = (const float4*)(cb + (size_t)(bid * 64 + r) * DIM + q * 64);
#pragma unroll
    for (int j = 0; j < 16; ++j) {
      float4 v = cp[j];
      int d = q * 64 + j * 4;
      cbs[r][d]     = v.x;
      cbs[r][d + 1] = v.y;
      cbs[r][d + 2] = v.z;
      cbs[r][d + 3] = v.w;
    }
  }
  const double cn = cn64[bid * 64 + lane];

  const int nit = (cnt + 3) >> 2;
  for (int it = 0; it < nit; ++it) {
    __syncthreads();   // cbs ready (it=0) / xr reuse safe (it>0)
    {
      int rr = it * 4 + w;
      if (rr < cnt) {
        int row = rlist[rr] & 16383;
        int bb = row >> 11, nn = row & (NSEQ - 1);
#pragma unroll
        for (int j = 0; j < 4; ++j) {
          int d = lane * 4 + j;
          xr[w][d] = x[((size_t)(bb << 8) + d) * NSEQ + nn];
        }
      }
    }
    __syncthreads();
    int rr = it * 4 + w;
    if (rr < cnt) {
      double dot = 0.0;
#pragma unroll 8
      for (int d4 = 0; d4 < DIM / 4; ++d4) {
        float4 cv = *(const float4*)&cbs[lane][d4 * 4];
        float4 xv = *(const float4*)&xr[w][d4 * 4];
        dot += (double)xv.x * cv.x + (double)xv.y * cv.y +
               (double)xv.z * cv.z + (double)xv.w * cv.w;
      }
      double best = cn - 2.0 * dot;
      int    bi   = bid * 64 + lane;
#pragma unroll
      for (int off = 1; off < 64; off <<= 1) {
        double ob = __shfl_xor(best, off, 64);
        int    oi = __shfl_xor(bi, off, 64);
        if (ob < best || (ob == best && oi < bi)) { best = ob; bi = oi; }
      }
      if (lane == 0) cand[rr * 64 + bid] = make_double2(best, (double)bi);
    }
  }
}

// ---- rescreen stage B: merge 64 slice-candidates per row; fix changed rows --
__global__ __launch_bounds__(256) void fsq_rescr_b(
    const float* __restrict__ x, const float* __restrict__ cb,
    const int* __restrict__ rcount, const int* __restrict__ rlist,
    const int* __restrict__ idxws, const double2* __restrict__ cand,
    float* __restrict__ out) {
  int cnt = *rcount;
  if (cnt > RCAP) cnt = RCAP;
  if (cnt <= 0) return;

  const int t    = threadIdx.x;
  const int w    = t >> 6;
  const int lane = t & 63;

  for (int rr = w; rr < cnt; rr += 4) {
    int row = rlist[rr] & 16383;
    double2 e = cand[rr * 64 + lane];
    double best = e.x;
    int    bi   = (int)e.y;
#pragma unroll
    for (int off = 1; off < 64; off <<= 1) {
      double ob = __shfl_xor(best, off, 64);
      int    oi = __shfl_xor(bi, off, 64);
      if (ob < best || (ob == best && oi < bi)) { best = ob; bi = oi; }
    }
    int enc = idxws[row];
    int old = (enc < 0) ? -(enc + 1) : enc;
    if (bi != old) {
      int bb = row >> 11, nn = row & (NSEQ - 1);
      if (lane == 0) out[IDXOFF + row] = (float)bi;
      float delta = 0.f;
#pragma unroll
      for (int j = 0; j < 4; ++j) {
        int d = lane * 4 + j;
        float qn = cb[(size_t)bi  * DIM + d];
        float qo = cb[(size_t)old * DIM + d];
        float xv = x[((size_t)(bb << 8) + d) * NSEQ + nn];
        out[((size_t)(bb << 8) + d) * NSEQ + nn] = qn;
        float d1 = qn - xv, d0 = qo - xv;
        delta += d1 * d1 - d0 * d0;
      }
#pragma unroll
      for (int off = 1; off < 64; off <<= 1) delta += __shfl_xor(delta, off, 64);
      if (lane == 0) atomicAdd(out + LOSS_OFF, delta * LOSS_SCALE);
    }
  }
}

extern "C" void kernel_launch(void* const* d_in, const int* in_sizes, int n_in,
                              void* d_out, int out_size, void* d_ws, size_t ws_size,
                              hipStream_t stream) {
  const float* x  = (const float*)d_in[0];   // [8, 256, 2048]
  const float* cb = (const float*)d_in[1];   // [4096, 256]
  float* out = (float*)d_out;

  char* wsb = (char*)d_ws;
  int*     rcount  = (int*)(wsb + 8);
  float*   cn32    = (float*)(wsb + 4096);                        // 16 KB
  double*  cn64    = (double*)(wsb + 4096 + 16384);               // 32 KB
  int*     idxws   = (int*)(wsb + 4096 + 16384 + 32768);          // 64 KB
  int*     rlist   = (int*)(wsb + 4096 + 16384 + 32768 + 65536);  // 2 KB
  char*    cbsplit = wsb + 131072;                                // 4 MB
  double2* cand    = (double2*)(wsb + 131072 + 4194304);          // 512 KB

  fsq_prep<<<528, 256, 0, stream>>>(cb, cbsplit, cn32, cn64, rcount, out);
  fsq_score<<<256, 512, 0, stream>>>(x, cb, cbsplit, cn32, idxws, rcount, rlist, out);
  fsq_rescr_a<<<64, 256, 0, stream>>>(x, cb, cn64, rcount, rlist, cand);
  fsq_rescr_b<<<1, 256, 0, stream>>>(x, cb, rcount, rlist, idxws, cand, out);
}